// Round 1
// baseline (517.383 us; speedup 1.0000x reference)
//
#include <hip/hip_runtime.h>

// SelfAttentionWithLeads: B=32, H=12, W=256, C=256, SPLIT=3 -> hs=4, N=1024,
// d_qk = 96, d_v = 768. All matmuls via mfma_f32_16x16x32_bf16.
//
// d_ws layout (bytes), total 63,340,544 (~63.3 MB):
//   Wt   @ 0         : [320][256] bf16  (Wf|Wg|Wh transposed)   163,840
//   f_fl @ 163840    : [32][1024][96] bf16                     6,291,456
//   g_fl @ 6455296   : [32][1024][96] bf16                     6,291,456
//   h_t  @ 12746752  : [32][768][1024] bf16 (pre-transposed)  50,331,648
//   sm   @ 63078400  : [32][1024] f32 row max                    131,072
//   sl   @ 63209472  : [32][1024] f32 1/row-sum-exp              131,072

typedef __bf16 bf16x8 __attribute__((ext_vector_type(8)));
typedef float f32x4 __attribute__((ext_vector_type(4)));

#define MFMA16 __builtin_amdgcn_mfma_f32_16x16x32_bf16

__device__ __forceinline__ short f2bf(float f) {
    unsigned u = __builtin_bit_cast(unsigned, f);
    u += 0x7fffu + ((u >> 16) & 1u);   // round-to-nearest-even
    return (short)(u >> 16);
}

// ---------------------------------------------------------------- weights ---
__global__ __launch_bounds__(256) void wt_kernel(const float* __restrict__ Wf,
                                                 const float* __restrict__ Wg,
                                                 const float* __restrict__ Wh,
                                                 short* __restrict__ Wt) {
    int t = blockIdx.x * 256 + threadIdx.x;   // 0..81919
    int j = t >> 8, k = t & 255;
    float v;
    if (j < 32)      v = Wf[k * 32 + j];
    else if (j < 64) v = Wg[k * 32 + (j - 32)];
    else             v = Wh[k * 256 + (j - 64)];
    Wt[j * 256 + k] = f2bf(v);
}

// ------------------------------------------------------------- projections --
// One block = 64 consecutive pixels (same b, same hh). Stages x tile in LDS
// (bf16, padded row stride 264 shorts -> 2-way bank aliasing only).
__global__ __launch_bounds__(256) void proj_kernel(const float* __restrict__ x,
                                                   const short* __restrict__ Wt,
                                                   short* __restrict__ f_fl,
                                                   short* __restrict__ g_fl,
                                                   short* __restrict__ h_t) {
    const int tid = threadIdx.x;
    const int P0  = blockIdx.x * 64;          // pixel base
    const int b   = P0 / 3072;
    const int rem = P0 % 3072;
    const int hh  = rem >> 8;
    const int wbase = rem & 255;
    const int lead = hh >> 2, hsi = hh & 3;
    const int nbase = hsi * 256 + wbase;

    __shared__ short xs[64][264];

    // stage x -> bf16 LDS
    const float4* xv = (const float4*)(x + (size_t)P0 * 256);
    #pragma unroll
    for (int i = 0; i < 16; ++i) {
        int idx = i * 256 + tid;              // float4 index in tile (0..4095)
        float4 v = xv[idx];
        int pix = idx >> 6;
        int col = (idx & 63) * 4;
        *(short4*)&xs[pix][col] =
            make_short4(f2bf(v.x), f2bf(v.y), f2bf(v.z), f2bf(v.w));
    }
    __syncthreads();

    const int lane = tid & 63, wv = tid >> 6;
    const int quad = lane >> 4, l15 = lane & 15;

    // ---- phase 1: f,g  (rows = 16 pixels per wave, cols j = 0..63) ----
    {
        f32x4 acc[4] = {};
        #pragma unroll
        for (int ki = 0; ki < 8; ++ki) {
            bf16x8 a = *(const bf16x8*)&xs[wv * 16 + l15][ki * 32 + quad * 8];
            #pragma unroll
            for (int jg = 0; jg < 4; ++jg) {
                bf16x8 bb = *(const bf16x8*)&Wt[(jg * 16 + l15) * 256 + ki * 32 + quad * 8];
                acc[jg] = MFMA16(a, bb, acc[jg], 0, 0, 0);
            }
        }
        #pragma unroll
        for (int jg = 0; jg < 4; ++jg) {
            int j = jg * 16 + l15;
            #pragma unroll
            for (int r = 0; r < 4; ++r) {
                int pix = wv * 16 + quad * 4 + r;
                int n = nbase + pix;
                short val = f2bf(acc[jg][r]);
                if (jg < 2)
                    f_fl[((size_t)b * 1024 + n) * 96 + lead * 32 + j] = val;
                else
                    g_fl[((size_t)b * 1024 + n) * 96 + lead * 32 + (j - 32)] = val;
            }
        }
    }

    // ---- phase 2: h_t = Wh^T * X^T  (rows = 64 out-channels per wave) ----
    {
        f32x4 acc[4][4] = {};
        #pragma unroll
        for (int ki = 0; ki < 8; ++ki) {
            bf16x8 a[4], bb[4];
            #pragma unroll
            for (int rf = 0; rf < 4; ++rf)
                a[rf] = *(const bf16x8*)&Wt[(64 + wv * 64 + rf * 16 + l15) * 256 + ki * 32 + quad * 8];
            #pragma unroll
            for (int pg = 0; pg < 4; ++pg)
                bb[pg] = *(const bf16x8*)&xs[pg * 16 + l15][ki * 32 + quad * 8];
            #pragma unroll
            for (int rf = 0; rf < 4; ++rf)
                #pragma unroll
                for (int pg = 0; pg < 4; ++pg)
                    acc[rf][pg] = MFMA16(a[rf], bb[pg], acc[rf][pg], 0, 0, 0);
        }
        const size_t hbase = ((size_t)b * 768 + lead * 256) * 1024 + nbase;
        #pragma unroll
        for (int rf = 0; rf < 4; ++rf)
            #pragma unroll
            for (int pg = 0; pg < 4; ++pg)
                #pragma unroll
                for (int r = 0; r < 4; ++r) {
                    int cc = wv * 64 + rf * 16 + quad * 4 + r;
                    int pix = pg * 16 + l15;
                    h_t[hbase + (size_t)cc * 1024 + pix] = f2bf(acc[rf][pg][r]);
                }
    }
}

// ---------------------------------------------------------- softmax stats ---
// Per wave: 16 query rows, online max / sum-exp over all 1024 keys.
__global__ __launch_bounds__(256) void stats_kernel(const short* __restrict__ f_fl,
                                                    const short* __restrict__ g_fl,
                                                    float* __restrict__ sm,
                                                    float* __restrict__ sl) {
    const int qb = blockIdx.x, b = blockIdx.y;
    const int tid = threadIdx.x, lane = tid & 63, wv = tid >> 6;
    const int quad = lane >> 4, l15 = lane & 15;
    const int qbase = qb * 64 + wv * 16;
    const short* gB = g_fl + (size_t)b * 1024 * 96;
    const short* fB = f_fl + (size_t)b * 1024 * 96;

    bf16x8 ga[3];
    #pragma unroll
    for (int ki = 0; ki < 3; ++ki)
        ga[ki] = *(const bf16x8*)&gB[(qbase + l15) * 96 + ki * 32 + quad * 8];

    float mrow[4], lrow[4];
    #pragma unroll
    for (int r = 0; r < 4; ++r) { mrow[r] = -1e30f; lrow[r] = 0.f; }

    for (int mt = 0; mt < 32; ++mt) {
        int m0 = mt * 32;
        f32x4 s[2] = {};
        #pragma unroll
        for (int cg = 0; cg < 2; ++cg)
            #pragma unroll
            for (int ki = 0; ki < 3; ++ki) {
                bf16x8 fb = *(const bf16x8*)&fB[(m0 + cg * 16 + l15) * 96 + ki * 32 + quad * 8];
                s[cg] = MFMA16(ga[ki], fb, s[cg], 0, 0, 0);
            }
        #pragma unroll
        for (int r = 0; r < 4; ++r) {
            float v = fmaxf(s[0][r], s[1][r]);
            #pragma unroll
            for (int d = 1; d < 16; d <<= 1) v = fmaxf(v, __shfl_xor(v, d));
            float nm = fmaxf(mrow[r], v);
            float e = __expf(s[0][r] - nm) + __expf(s[1][r] - nm);
            #pragma unroll
            for (int d = 1; d < 16; d <<= 1) e += __shfl_xor(e, d);
            lrow[r] = lrow[r] * __expf(mrow[r] - nm) + e;
            mrow[r] = nm;
        }
    }
    if (l15 == 0) {
        #pragma unroll
        for (int r = 0; r < 4; ++r) {
            int row = qbase + quad * 4 + r;
            sm[b * 1024 + row] = mrow[r];
            sl[b * 1024 + row] = 1.0f / lrow[r];
        }
    }
}

// ----------------------------------------------------------------- attend ---
// grid (vb=4, qb=8, b=32). Wave = 32 q-rows x 192 v-cols. Per 32-key tile:
// S via MFMA, P = exp(s-m)/l, C->A layout transpose through per-wave LDS,
// PV via MFMA, fused recover + gamma*o + x epilogue.
__global__ __launch_bounds__(256, 2) void attn_kernel(const short* __restrict__ f_fl,
                                                      const short* __restrict__ g_fl,
                                                      const short* __restrict__ h_t,
                                                      const float* __restrict__ sm,
                                                      const float* __restrict__ sl,
                                                      const float* __restrict__ x,
                                                      const float* __restrict__ gammap,
                                                      float* __restrict__ out) {
    const int vb = blockIdx.x, qb = blockIdx.y, b = blockIdx.z;
    const int tid = threadIdx.x, lane = tid & 63, wv = tid >> 6;
    const int quad = lane >> 4, l15 = lane & 15;
    const int wq = qb * 128 + wv * 32;
    const short* gB = g_fl + (size_t)b * 1024 * 96;
    const short* fB = f_fl + (size_t)b * 1024 * 96;
    const short* hB = h_t + (size_t)b * 768 * 1024;

    // per-wave P buffer; row stride 40 shorts = 80 B (16B-aligned, bank-friendly)
    __shared__ short plds[4][32][40];

    bf16x8 ga[2][3];
    #pragma unroll
    for (int qf = 0; qf < 2; ++qf)
        #pragma unroll
        for (int ki = 0; ki < 3; ++ki)
            ga[qf][ki] = *(const bf16x8*)&gB[(wq + qf * 16 + l15) * 96 + ki * 32 + quad * 8];

    float ms[2][4], li[2][4];
    #pragma unroll
    for (int qf = 0; qf < 2; ++qf)
        #pragma unroll
        for (int r = 0; r < 4; ++r) {
            int row = wq + qf * 16 + quad * 4 + r;
            ms[qf][r] = sm[b * 1024 + row];
            li[qf][r] = sl[b * 1024 + row];
        }

    f32x4 o[2][12] = {};

    for (int mt = 0; mt < 32; ++mt) {
        int m0 = mt * 32;
        f32x4 s[2][2] = {};
        #pragma unroll
        for (int mf = 0; mf < 2; ++mf)
            #pragma unroll
            for (int ki = 0; ki < 3; ++ki) {
                bf16x8 fb = *(const bf16x8*)&fB[(m0 + mf * 16 + l15) * 96 + ki * 32 + quad * 8];
                #pragma unroll
                for (int qf = 0; qf < 2; ++qf)
                    s[qf][mf] = MFMA16(ga[qf][ki], fb, s[qf][mf], 0, 0, 0);
            }
        // P = exp(s - m) / l  -> LDS (C-layout write)
        #pragma unroll
        for (int qf = 0; qf < 2; ++qf)
            #pragma unroll
            for (int mf = 0; mf < 2; ++mf)
                #pragma unroll
                for (int r = 0; r < 4; ++r) {
                    float p = __expf(s[qf][mf][r] - ms[qf][r]) * li[qf][r];
                    plds[wv][qf * 16 + quad * 4 + r][mf * 16 + l15] = f2bf(p);
                }
        // A-layout read (wave-local; compiler inserts lgkmcnt waits)
        bf16x8 pa[2];
        #pragma unroll
        for (int qf = 0; qf < 2; ++qf)
            pa[qf] = *(const bf16x8*)&plds[wv][qf * 16 + l15][quad * 8];
        // PV
        #pragma unroll
        for (int g = 0; g < 12; ++g) {
            int vc = vb * 192 + g * 16 + l15;
            bf16x8 hv = *(const bf16x8*)&hB[(size_t)vc * 1024 + m0 + quad * 8];
            o[0][g] = MFMA16(pa[0], hv, o[0][g], 0, 0, 0);
            o[1][g] = MFMA16(pa[1], hv, o[1][g], 0, 0, 0);
        }
    }

    const float gamma = gammap[0];
    #pragma unroll
    for (int qf = 0; qf < 2; ++qf)
        #pragma unroll
        for (int g = 0; g < 12; ++g) {
            int vc = vb * 192 + g * 16 + l15;
            int lead = vc >> 8, c = vc & 255;
            #pragma unroll
            for (int r = 0; r < 4; ++r) {
                int n = wq + qf * 16 + quad * 4 + r;
                int hsi = n >> 8, w_ = n & 255;
                size_t idx = (((size_t)b * 12 + lead * 4 + hsi) * 256 + w_) * 256 + c;
                out[idx] = gamma * o[qf][g][r] + x[idx];
            }
        }
}

// ------------------------------------------------------------------ launch --
extern "C" void kernel_launch(void* const* d_in, const int* in_sizes, int n_in,
                              void* d_out, int out_size, void* d_ws, size_t ws_size,
                              hipStream_t stream) {
    const float* x     = (const float*)d_in[0];
    const float* Wf    = (const float*)d_in[1];
    const float* Wg    = (const float*)d_in[2];
    const float* Wh    = (const float*)d_in[3];
    const float* gamma = (const float*)d_in[4];
    float* out = (float*)d_out;

    char* ws = (char*)d_ws;
    short* Wt   = (short*)(ws + 0);
    short* f_fl = (short*)(ws + 163840);
    short* g_fl = (short*)(ws + 6455296);
    short* h_t  = (short*)(ws + 12746752);
    float* sm   = (float*)(ws + 63078400);
    float* sl   = (float*)(ws + 63209472);

    wt_kernel<<<dim3(320), dim3(256), 0, stream>>>(Wf, Wg, Wh, Wt);
    proj_kernel<<<dim3(1536), dim3(256), 0, stream>>>(x, Wt, f_fl, g_fl, h_t);
    stats_kernel<<<dim3(16, 32), dim3(256), 0, stream>>>(f_fl, g_fl, sm, sl);
    attn_kernel<<<dim3(4, 8, 32), dim3(256), 0, stream>>>(f_fl, g_fl, h_t, sm, sl, x, gamma, out);
}